// Round 1
// baseline (104.453 us; speedup 1.0000x reference)
//
#include <hip/hip_runtime.h>
#include <hip/hip_bf16.h>

#define N 4096
#define D 512
#define MARGIN 0.5f
#define BETA 10.0f

typedef __attribute__((ext_vector_type(8))) short short8;
typedef __attribute__((ext_vector_type(4))) float floatx4;

__device__ inline unsigned short f2bf(float f) {
    unsigned u = __float_as_uint(f);
    u += 0x7fffu + ((u >> 16) & 1u);   // round-to-nearest-even
    return (unsigned short)(u >> 16);
}

// ---- Kernel 1: f32 -> bf16 convert (N*D elements, 4 per thread) ----
__global__ void convert_bf16_kernel(const float4* __restrict__ in,
                                    ushort4* __restrict__ out) {
    int idx = blockIdx.x * 256 + threadIdx.x;
    float4 v = in[idx];
    ushort4 o;
    o.x = f2bf(v.x); o.y = f2bf(v.y); o.z = f2bf(v.z); o.w = f2bf(v.w);
    out[idx] = o;
}

// ---- Kernel 2: fused sim-GEMM + masked exp row-sums ----
// Grid: (32, 32) blocks of 256 threads. Block (bx,by) computes the
// 128x128 tile sim[by*128 .. , bx*128 ..] and accumulates
// pos_sum/neg_sum for its 128 rows via atomicAdd.
__global__ void ms_loss_gemm(const unsigned short* __restrict__ Ebf,
                             const int* __restrict__ labels,
                             float* __restrict__ pos_sum,
                             float* __restrict__ neg_sum) {
    __shared__ unsigned short Atile[128 * 32];   // [row][k] bf16, 8 KB
    __shared__ unsigned short Btile[128 * 32];   // [col][k] bf16, 8 KB
    __shared__ int rlab[128];
    __shared__ int clab[128];

    const int tid  = threadIdx.x;
    const int wave = tid >> 6;
    const int lane = tid & 63;
    const int quad = lane >> 4;      // 0..3
    const int lcol = lane & 15;      // 0..15
    const int wrow = wave >> 1;      // 0..1
    const int wcol = wave & 1;       // 0..1
    const int ibase = blockIdx.y * 128;
    const int jbase = blockIdx.x * 128;

    if (tid < 128)       rlab[tid]       = labels[ibase + tid];
    else                 clab[tid - 128] = labels[jbase + tid - 128];

    floatx4 acc[4][4];
#pragma unroll
    for (int mt = 0; mt < 4; ++mt)
#pragma unroll
        for (int nt = 0; nt < 4; ++nt)
            acc[mt][nt] = (floatx4){0.f, 0.f, 0.f, 0.f};

    const char* Eb = (const char*)Ebf;           // row stride = D*2 = 1024 B
    char* Ab = (char*)Atile;
    char* Bb = (char*)Btile;
    const int srow = lane >> 2;                  // 0..15
    const int skb  = (lane & 3) * 16;            // byte offset in k-chunk row

    for (int kt = 0; kt < D / 32; ++kt) {
        __syncthreads();   // previous iter's ds_reads done before overwrite
        const int kb = kt * 64;                  // byte offset of k-chunk
#pragma unroll
        for (int it = 0; it < 2; ++it) {
            int r    = wave * 16 + it * 64 + srow;          // 0..127
            int ldso = wave * 1024 + it * 4096 + lane * 16; // contiguous
            const char* ga = Eb + (size_t)(ibase + r) * (D * 2) + kb + skb;
            const char* gb = Eb + (size_t)(jbase + r) * (D * 2) + kb + skb;
            __builtin_amdgcn_global_load_lds(
                (const __attribute__((address_space(1))) void*)ga,
                (__attribute__((address_space(3))) void*)(Ab + ldso), 16, 0, 0);
            __builtin_amdgcn_global_load_lds(
                (const __attribute__((address_space(1))) void*)gb,
                (__attribute__((address_space(3))) void*)(Bb + ldso), 16, 0, 0);
        }
        __syncthreads();   // drains vmcnt before any frag read

        short8 a[4], b[4];
#pragma unroll
        for (int mt = 0; mt < 4; ++mt) {
            int r = wrow * 64 + mt * 16 + lcol;
            a[mt] = *(const short8*)(Ab + r * 64 + quad * 16);
        }
#pragma unroll
        for (int nt = 0; nt < 4; ++nt) {
            int c = wcol * 64 + nt * 16 + lcol;
            b[nt] = *(const short8*)(Bb + c * 64 + quad * 16);
        }
#pragma unroll
        for (int mt = 0; mt < 4; ++mt)
#pragma unroll
            for (int nt = 0; nt < 4; ++nt)
                acc[mt][nt] = __builtin_amdgcn_mfma_f32_16x16x32_bf16(
                    a[mt], b[nt], acc[mt][nt], 0, 0, 0);
    }

    // ---- epilogue: masked exp, per-lane partial row sums ----
    // C layout (m89-verified): col = lane&15, row = quad*4 + reg
    float pacc[16], nacc[16];
#pragma unroll
    for (int t = 0; t < 16; ++t) { pacc[t] = 0.f; nacc[t] = 0.f; }

#pragma unroll
    for (int mt = 0; mt < 4; ++mt) {
#pragma unroll
        for (int nt = 0; nt < 4; ++nt) {
            int cl = wcol * 64 + nt * 16 + lcol;
            int gj = jbase + cl;
            int lj = clab[cl];
#pragma unroll
            for (int reg = 0; reg < 4; ++reg) {
                int rl = wrow * 64 + mt * 16 + quad * 4 + reg;
                int gi = ibase + rl;
                float s = acc[mt][nt][reg];
                if (gi != gj) {
                    if (rlab[rl] == lj)
                        pacc[mt * 4 + reg] += __expf(MARGIN - s);          // alpha=1
                    else
                        nacc[mt * 4 + reg] += __expf(BETA * (s - MARGIN));
                }
            }
        }
    }

    // reduce across the 16 lanes of each quad (they hold different cols)
#pragma unroll
    for (int t = 0; t < 16; ++t) {
        float p = pacc[t], ng = nacc[t];
        p += __shfl_xor(p, 1);  ng += __shfl_xor(ng, 1);
        p += __shfl_xor(p, 2);  ng += __shfl_xor(ng, 2);
        p += __shfl_xor(p, 4);  ng += __shfl_xor(ng, 4);
        p += __shfl_xor(p, 8);  ng += __shfl_xor(ng, 8);
        if (lcol == 0) {
            int mt = t >> 2, reg = t & 3;
            int gi = ibase + wrow * 64 + mt * 16 + quad * 4 + reg;
            atomicAdd(&pos_sum[gi], p);
            atomicAdd(&neg_sum[gi], ng);
        }
    }
}

// ---- Kernel 3: finalize ----
__global__ void finalize_kernel(const float* __restrict__ pos_sum,
                                const float* __restrict__ neg_sum,
                                float* __restrict__ out) {
    __shared__ float sb[256];
    __shared__ int   sc[256];
    const int tid = threadIdx.x;
    float tot = 0.f;
    int cnt = 0;
    for (int i = tid; i < N; i += 256) {
        float p = pos_sum[i], ng = neg_sum[i];
        if (p > 0.f && ng > 0.f) {
            tot += log1pf(p) + (1.0f / BETA) * log1pf(ng);
            cnt += 1;
        }
    }
    sb[tid] = tot; sc[tid] = cnt;
    __syncthreads();
    for (int s = 128; s > 0; s >>= 1) {
        if (tid < s) { sb[tid] += sb[tid + s]; sc[tid] += sc[tid + s]; }
        __syncthreads();
    }
    if (tid == 0) out[0] = (sc[0] > 0) ? sb[0] / (float)sc[0] : 0.f;
}

extern "C" void kernel_launch(void* const* d_in, const int* in_sizes, int n_in,
                              void* d_out, int out_size, void* d_ws, size_t ws_size,
                              hipStream_t stream) {
    const float* emb   = (const float*)d_in[0];
    const int* labels  = (const int*)d_in[1];
    float* out         = (float*)d_out;

    char* ws = (char*)d_ws;
    unsigned short* Ebf = (unsigned short*)ws;                 // 4 MB
    float* pos_sum = (float*)(ws + (size_t)N * D * 2);         // 16 KB
    float* neg_sum = pos_sum + N;                              // 16 KB

    hipMemsetAsync(pos_sum, 0, 2 * N * sizeof(float), stream);

    convert_bf16_kernel<<<(N * D / 4) / 256, 256, 0, stream>>>(
        (const float4*)emb, (ushort4*)Ebf);

    dim3 grid(N / 128, N / 128);
    ms_loss_gemm<<<grid, 256, 0, stream>>>(Ebf, labels, pos_sum, neg_sum);

    finalize_kernel<<<1, 256, 0, stream>>>(pos_sum, neg_sum, out);
}

// Round 2
// 99.853 us; speedup vs baseline: 1.0461x; 1.0461x over previous
//
#include <hip/hip_runtime.h>
#include <hip/hip_bf16.h>

#define N 4096
#define D 512
#define MARGIN 0.5f
#define BETA 10.0f

typedef __attribute__((ext_vector_type(8))) short short8;
typedef __attribute__((ext_vector_type(4))) float floatx4;

__device__ inline unsigned short f2bf(float f) {
    unsigned u = __float_as_uint(f);
    u += 0x7fffu + ((u >> 16) & 1u);   // round-to-nearest-even
    return (unsigned short)(u >> 16);
}

// ---- Kernel 1: f32 -> bf16 convert + zero the accumulator buffers ----
__global__ __launch_bounds__(256) void convert_bf16_kernel(
        const float4* __restrict__ in, ushort4* __restrict__ out,
        float* __restrict__ sums /* 2*N floats to zero */) {
    int idx = blockIdx.x * 256 + threadIdx.x;
    if (idx < 2 * N) sums[idx] = 0.f;       // blocks 0..31 zero pos/neg sums
    float4 v = in[idx];
    ushort4 o;
    o.x = f2bf(v.x); o.y = f2bf(v.y); o.z = f2bf(v.z); o.w = f2bf(v.w);
    out[idx] = o;
}

// ---- Kernel 2: fused sim-GEMM + masked exp row-sums ----
// Grid (32,32) x 256 threads; block (bx,by) does the 128x128 tile
// sim[by*128.., bx*128..]. LDS chunk-XOR swizzle: 16B slot (r,c) holds
// global chunk c ^ ((r>>1)&3) so ds_read_b128 phases are 2-way (free).
__global__ __launch_bounds__(256, 4) void ms_loss_gemm(
        const unsigned short* __restrict__ Ebf,
        const int* __restrict__ labels,
        float* __restrict__ pos_sum,
        float* __restrict__ neg_sum) {
    __shared__ unsigned short Atile[128 * 32];   // 8 KB
    __shared__ unsigned short Btile[128 * 32];   // 8 KB
    __shared__ int rlab[128];
    __shared__ int clab[128];

    const int tid  = threadIdx.x;
    const int wave = tid >> 6;
    const int lane = tid & 63;
    const int quad = lane >> 4;      // 0..3
    const int lcol = lane & 15;      // 0..15
    const int wrow = wave >> 1;      // 0..1
    const int wcol = wave & 1;       // 0..1
    const int ibase = blockIdx.y * 128;
    const int jbase = blockIdx.x * 128;

    if (tid < 128)       rlab[tid]       = labels[ibase + tid];
    else                 clab[tid - 128] = labels[jbase + tid - 128];

    floatx4 acc[4][4];
#pragma unroll
    for (int mt = 0; mt < 4; ++mt)
#pragma unroll
        for (int nt = 0; nt < 4; ++nt)
            acc[mt][nt] = (floatx4){0.f, 0.f, 0.f, 0.f};

    const char* Eb = (const char*)Ebf;           // row stride = 1024 B
    char* Ab = (char*)Atile;
    char* Bb = (char*)Btile;
    const int srow = lane >> 2;                       // local row 0..15 within chunk-of-16
    const int sckb = ((lane & 3) ^ ((lane >> 3) & 3)) * 16;  // swizzled global chunk
    const int rdsw = ((lcol >> 1) & 3);               // read-side XOR term

    for (int kt = 0; kt < D / 32; ++kt) {
        __syncthreads();   // previous iter's ds_reads done before overwrite
        const int kb = kt * 64;
#pragma unroll
        for (int it = 0; it < 2; ++it) {
            int r    = wave * 16 + it * 64 + srow;          // 0..127
            int ldso = wave * 1024 + it * 4096 + lane * 16; // contiguous (HW req)
            const char* ga = Eb + (size_t)(ibase + r) * (D * 2) + kb + sckb;
            const char* gb = Eb + (size_t)(jbase + r) * (D * 2) + kb + sckb;
            __builtin_amdgcn_global_load_lds(
                (const __attribute__((address_space(1))) void*)ga,
                (__attribute__((address_space(3))) void*)(Ab + ldso), 16, 0, 0);
            __builtin_amdgcn_global_load_lds(
                (const __attribute__((address_space(1))) void*)gb,
                (__attribute__((address_space(3))) void*)(Bb + ldso), 16, 0, 0);
        }
        __syncthreads();   // drains vmcnt before any frag read

        short8 a[4], b[4];
        const int rchunk = (quad ^ rdsw) * 16;
#pragma unroll
        for (int mt = 0; mt < 4; ++mt) {
            int r = wrow * 64 + mt * 16 + lcol;
            a[mt] = *(const short8*)(Ab + r * 64 + rchunk);
        }
#pragma unroll
        for (int nt = 0; nt < 4; ++nt) {
            int c = wcol * 64 + nt * 16 + lcol;
            b[nt] = *(const short8*)(Bb + c * 64 + rchunk);
        }
#pragma unroll
        for (int mt = 0; mt < 4; ++mt)
#pragma unroll
            for (int nt = 0; nt < 4; ++nt)
                acc[mt][nt] = __builtin_amdgcn_mfma_f32_16x16x32_bf16(
                    a[mt], b[nt], acc[mt][nt], 0, 0, 0);
    }

    // ---- epilogue: masked exp, per-row partial sums ----
    // C layout (m89-verified): col = lane&15, row = quad*4 + reg
    int ljv[4], gjv[4];
#pragma unroll
    for (int nt = 0; nt < 4; ++nt) {
        int cl = wcol * 64 + nt * 16 + lcol;
        ljv[nt] = clab[cl];
        gjv[nt] = jbase + cl;
    }

#pragma unroll
    for (int mt = 0; mt < 4; ++mt) {
#pragma unroll
        for (int reg = 0; reg < 4; ++reg) {
            int rl = wrow * 64 + mt * 16 + quad * 4 + reg;
            int gi = ibase + rl;
            int li = rlab[rl];
            float p = 0.f, ng = 0.f;
#pragma unroll
            for (int nt = 0; nt < 4; ++nt) {
                float s = acc[mt][nt][reg];
                if (gi != gjv[nt]) {
                    if (li == ljv[nt])
                        p  += __expf(MARGIN - s);              // alpha = 1
                    else
                        ng += __expf(BETA * (s - MARGIN));
                }
            }
            // reduce across the 16 lanes of the quad (distinct cols)
            p  += __shfl_xor(p, 1);   ng += __shfl_xor(ng, 1);
            p  += __shfl_xor(p, 2);   ng += __shfl_xor(ng, 2);
            p  += __shfl_xor(p, 4);   ng += __shfl_xor(ng, 4);
            p  += __shfl_xor(p, 8);   ng += __shfl_xor(ng, 8);
            if (lcol == 0) {
                atomicAdd(&pos_sum[gi], p);
                atomicAdd(&neg_sum[gi], ng);
            }
        }
    }
}

// ---- Kernel 3: finalize ----
__global__ __launch_bounds__(256) void finalize_kernel(
        const float4* __restrict__ pos4, const float4* __restrict__ neg4,
        float* __restrict__ out) {
    __shared__ float sb[256];
    __shared__ int   sc[256];
    const int tid = threadIdx.x;
    float tot = 0.f;
    int cnt = 0;
#pragma unroll
    for (int it = 0; it < N / 4 / 256; ++it) {
        int i = it * 256 + tid;
        float4 p = pos4[i];
        float4 ng = neg4[i];
        const float* pp = (const float*)&p;
        const float* nn = (const float*)&ng;
#pragma unroll
        for (int j = 0; j < 4; ++j) {
            if (pp[j] > 0.f && nn[j] > 0.f) {
                tot += log1pf(pp[j]) + (1.0f / BETA) * log1pf(nn[j]);
                cnt += 1;
            }
        }
    }
    sb[tid] = tot; sc[tid] = cnt;
    __syncthreads();
    for (int s = 128; s > 0; s >>= 1) {
        if (tid < s) { sb[tid] += sb[tid + s]; sc[tid] += sc[tid + s]; }
        __syncthreads();
    }
    if (tid == 0) out[0] = (sc[0] > 0) ? sb[0] / (float)sc[0] : 0.f;
}

extern "C" void kernel_launch(void* const* d_in, const int* in_sizes, int n_in,
                              void* d_out, int out_size, void* d_ws, size_t ws_size,
                              hipStream_t stream) {
    const float* emb   = (const float*)d_in[0];
    const int* labels  = (const int*)d_in[1];
    float* out         = (float*)d_out;

    char* ws = (char*)d_ws;
    unsigned short* Ebf = (unsigned short*)ws;                 // 4 MB
    float* pos_sum = (float*)(ws + (size_t)N * D * 2);         // 16 KB
    float* neg_sum = pos_sum + N;                              // 16 KB

    convert_bf16_kernel<<<(N * D / 4) / 256, 256, 0, stream>>>(
        (const float4*)emb, (ushort4*)Ebf, pos_sum);

    dim3 grid(N / 128, N / 128);
    ms_loss_gemm<<<grid, 256, 0, stream>>>(Ebf, labels, pos_sum, neg_sum);

    finalize_kernel<<<1, 256, 0, stream>>>(
        (const float4*)pos_sum, (const float4*)neg_sum, out);
}

// Round 3
// 93.161 us; speedup vs baseline: 1.1212x; 1.0718x over previous
//
#include <hip/hip_runtime.h>
#include <hip/hip_bf16.h>

#define N 4096
#define D 512
#define MARGIN 0.5f
#define BETA 10.0f

typedef __attribute__((ext_vector_type(8))) short short8;
typedef __attribute__((ext_vector_type(4))) float floatx4;

__device__ inline unsigned short f2bf(float f) {
    unsigned u = __float_as_uint(f);
    u += 0x7fffu + ((u >> 16) & 1u);   // round-to-nearest-even
    return (unsigned short)(u >> 16);
}

// ---- Kernel 1: f32 -> bf16 convert + zero the accumulator buffers ----
__global__ __launch_bounds__(256) void convert_bf16_kernel(
        const float4* __restrict__ in, ushort4* __restrict__ out,
        float* __restrict__ sums /* 2*N floats to zero */) {
    int idx = blockIdx.x * 256 + threadIdx.x;
    if (idx < 2 * N) sums[idx] = 0.f;
    float4 v = in[idx];
    ushort4 o;
    o.x = f2bf(v.x); o.y = f2bf(v.y); o.z = f2bf(v.z); o.w = f2bf(v.w);
    out[idx] = o;
}

// ---- Kernel 2: fused sim-GEMM + masked exp sums, UPPER-TRIANGLE only ----
// sim = E.E^T is symmetric: block t decodes to tile (bi<=bj) and credits
// rows ibase.. (sum over cols) AND rows jbase.. (sum over rows) with the
// same exp values. 528 blocks instead of 1024 (48% less MFMA+staging).
__global__ __launch_bounds__(256, 4) void ms_loss_gemm(
        const unsigned short* __restrict__ Ebf,
        const int* __restrict__ labels,
        float* __restrict__ pos_sum,
        float* __restrict__ neg_sum) {
    __shared__ unsigned short Atile[128 * 32];   // 8 KB
    __shared__ unsigned short Btile[128 * 32];   // 8 KB
    __shared__ int rlab[128];
    __shared__ int clab[128];

    // decode linear block id -> upper-triangle tile (bi, bj), bi <= bj
    int t = blockIdx.x;
    int bi = 0;
    while (t >= (32 - bi)) { t -= (32 - bi); ++bi; }
    const int bj = bi + t;
    const bool diag = (bi == bj);

    const int tid  = threadIdx.x;
    const int wave = tid >> 6;
    const int lane = tid & 63;
    const int quad = lane >> 4;      // 0..3
    const int lcol = lane & 15;      // 0..15
    const int wrow = wave >> 1;      // 0..1
    const int wcol = wave & 1;       // 0..1
    const int ibase = bi * 128;
    const int jbase = bj * 128;

    if (tid < 128)       rlab[tid]       = labels[ibase + tid];
    else                 clab[tid - 128] = labels[jbase + tid - 128];

    floatx4 acc[4][4];
#pragma unroll
    for (int mt = 0; mt < 4; ++mt)
#pragma unroll
        for (int nt = 0; nt < 4; ++nt)
            acc[mt][nt] = (floatx4){0.f, 0.f, 0.f, 0.f};

    const char* Eb = (const char*)Ebf;           // row stride = 1024 B
    char* Ab = (char*)Atile;
    char* Bb = (char*)Btile;
    const char* Bread = diag ? Ab : Bb;          // diag: B-frags come from Atile
    const int srow = lane >> 2;                       // 0..15
    const int sckb = ((lane & 3) ^ ((lane >> 3) & 3)) * 16;  // swizzled chunk
    const int rdsw = ((lcol >> 1) & 3);               // read-side XOR term

    for (int kt = 0; kt < D / 32; ++kt) {
        __syncthreads();
        const int kb = kt * 64;
#pragma unroll
        for (int it = 0; it < 2; ++it) {
            int r    = wave * 16 + it * 64 + srow;          // 0..127
            int ldso = wave * 1024 + it * 4096 + lane * 16; // contiguous (HW req)
            const char* ga = Eb + (size_t)(ibase + r) * (D * 2) + kb + sckb;
            __builtin_amdgcn_global_load_lds(
                (const __attribute__((address_space(1))) void*)ga,
                (__attribute__((address_space(3))) void*)(Ab + ldso), 16, 0, 0);
            if (!diag) {
                const char* gb = Eb + (size_t)(jbase + r) * (D * 2) + kb + sckb;
                __builtin_amdgcn_global_load_lds(
                    (const __attribute__((address_space(1))) void*)gb,
                    (__attribute__((address_space(3))) void*)(Bb + ldso), 16, 0, 0);
            }
        }
        __syncthreads();

        short8 a[4], b[4];
        const int rchunk = (quad ^ rdsw) * 16;
#pragma unroll
        for (int mt = 0; mt < 4; ++mt) {
            int r = wrow * 64 + mt * 16 + lcol;
            a[mt] = *(const short8*)(Ab + r * 64 + rchunk);
        }
#pragma unroll
        for (int nt = 0; nt < 4; ++nt) {
            int c = wcol * 64 + nt * 16 + lcol;
            b[nt] = *(const short8*)(Bread + c * 64 + rchunk);
        }
#pragma unroll
        for (int mt = 0; mt < 4; ++mt)
#pragma unroll
            for (int nt = 0; nt < 4; ++nt)
                acc[mt][nt] = __builtin_amdgcn_mfma_f32_16x16x32_bf16(
                    a[mt], b[nt], acc[mt][nt], 0, 0, 0);
    }

    // ---- epilogue ----
    // C layout (m89-verified): col = lane&15, row = quad*4 + reg
    int ljv[4], gjv[4];
#pragma unroll
    for (int nt = 0; nt < 4; ++nt) {
        int cl = wcol * 64 + nt * 16 + lcol;
        ljv[nt] = clab[cl];
        gjv[nt] = jbase + cl;
    }

    float colp[4] = {0.f, 0.f, 0.f, 0.f};
    float coln[4] = {0.f, 0.f, 0.f, 0.f};

#pragma unroll
    for (int mt = 0; mt < 4; ++mt) {
#pragma unroll
        for (int reg = 0; reg < 4; ++reg) {
            int rl = wrow * 64 + mt * 16 + quad * 4 + reg;
            int gi = ibase + rl;
            int li = rlab[rl];
            float p = 0.f, ng = 0.f;
#pragma unroll
            for (int nt = 0; nt < 4; ++nt) {
                float s = acc[mt][nt][reg];
                if (gi != gjv[nt]) {
                    if (li == ljv[nt]) {
                        float e = __expf(MARGIN - s);          // alpha = 1
                        p += e;  colp[nt] += e;
                    } else {
                        float e = __expf(BETA * (s - MARGIN));
                        ng += e; coln[nt] += e;
                    }
                }
            }
            // row-sum: reduce across the 16 lcol lanes (distinct cols)
            p  += __shfl_xor(p, 1);   ng += __shfl_xor(ng, 1);
            p  += __shfl_xor(p, 2);   ng += __shfl_xor(ng, 2);
            p  += __shfl_xor(p, 4);   ng += __shfl_xor(ng, 4);
            p  += __shfl_xor(p, 8);   ng += __shfl_xor(ng, 8);
            if (lcol == 0) {
                atomicAdd(&pos_sum[gi], p);
                atomicAdd(&neg_sum[gi], ng);
            }
        }
    }

    // col-sum (mirror credit), off-diagonal blocks only:
    // reduce across quads (xor 16,32); lane's col = nt*16+lcol.
    if (!diag) {
#pragma unroll
        for (int nt = 0; nt < 4; ++nt) {
            float cp = colp[nt], cn = coln[nt];
            cp += __shfl_xor(cp, 16);  cn += __shfl_xor(cn, 16);
            cp += __shfl_xor(cp, 32);  cn += __shfl_xor(cn, 32);
            if (quad == 0) {
                int gj = gjv[nt];
                atomicAdd(&pos_sum[gj], cp);
                atomicAdd(&neg_sum[gj], cn);
            }
        }
    }
}

// ---- Kernel 3: finalize ----
__global__ __launch_bounds__(256) void finalize_kernel(
        const float4* __restrict__ pos4, const float4* __restrict__ neg4,
        float* __restrict__ out) {
    __shared__ float sb[256];
    __shared__ int   sc[256];
    const int tid = threadIdx.x;
    float tot = 0.f;
    int cnt = 0;
#pragma unroll
    for (int it = 0; it < N / 4 / 256; ++it) {
        int i = it * 256 + tid;
        float4 p = pos4[i];
        float4 ng = neg4[i];
        const float* pp = (const float*)&p;
        const float* nn = (const float*)&ng;
#pragma unroll
        for (int j = 0; j < 4; ++j) {
            if (pp[j] > 0.f && nn[j] > 0.f) {
                tot += log1pf(pp[j]) + (1.0f / BETA) * log1pf(nn[j]);
                cnt += 1;
            }
        }
    }
    sb[tid] = tot; sc[tid] = cnt;
    __syncthreads();
    for (int s = 128; s > 0; s >>= 1) {
        if (tid < s) { sb[tid] += sb[tid + s]; sc[tid] += sc[tid + s]; }
        __syncthreads();
    }
    if (tid == 0) out[0] = (sc[0] > 0) ? sb[0] / (float)sc[0] : 0.f;
}

extern "C" void kernel_launch(void* const* d_in, const int* in_sizes, int n_in,
                              void* d_out, int out_size, void* d_ws, size_t ws_size,
                              hipStream_t stream) {
    const float* emb   = (const float*)d_in[0];
    const int* labels  = (const int*)d_in[1];
    float* out         = (float*)d_out;

    char* ws = (char*)d_ws;
    unsigned short* Ebf = (unsigned short*)ws;                 // 4 MB
    float* pos_sum = (float*)(ws + (size_t)N * D * 2);         // 16 KB
    float* neg_sum = pos_sum + N;                              // 16 KB

    convert_bf16_kernel<<<(N * D / 4) / 256, 256, 0, stream>>>(
        (const float4*)emb, (ushort4*)Ebf, pos_sum);

    ms_loss_gemm<<<(32 * 33) / 2, 256, 0, stream>>>(Ebf, labels, pos_sum, neg_sum);

    finalize_kernel<<<1, 256, 0, stream>>>(
        (const float4*)pos_sum, (const float4*)neg_sum, out);
}